// Round 2
// baseline (28949.283 us; speedup 1.0000x reference)
//
#include <hip/hip_runtime.h>
#include <hip/hip_bf16.h>
#include <stdint.h>

typedef float  f32x4  __attribute__((ext_vector_type(4)));
typedef short  bf16x8 __attribute__((ext_vector_type(8)));
typedef unsigned int  u32;
typedef unsigned short u16;
typedef unsigned long long u64;

#define BS    64
#define SEQ   1024
#define HID   512

// ---------- helpers ----------
__device__ __forceinline__ u16 f2bf(float f) {
    u32 u = __float_as_uint(f);
    u32 r = (u + 0x7FFFu + ((u >> 16) & 1u)) >> 16;   // RNE
    return (u16)r;
}
__device__ __forceinline__ float bf2f(u16 h) {
    return __uint_as_float(((u32)h) << 16);
}
__device__ __forceinline__ u32 pk2(float a, float b) {
    return (u32)f2bf(a) | ((u32)f2bf(b) << 16);
}
__device__ __forceinline__ float sigm(float x)  { return 1.f / (1.f + __expf(-x)); }
__device__ __forceinline__ float tanh_(float x) { return 1.f - 2.f / (1.f + __expf(2.f * x)); }

// ---------- ws layout ----------
// [0, 2MB)            w4t  bf16 [2048][512]
// [2MB, +8KB)         b4   f32  [2048]
// [.., +4KB)          flags int [8][16]  (64B stride)
// [.., +128KB)        hbuf u32  [2][4][16][256]   (2x bf16 packed)
// [.., +128KB)        cbuf f32  [4][16][512]
// [4MB, ...)          xp   bf16 [64*Tc][2048]
#define OFF_W4T   0
#define OFF_B4    (2u*1024*1024)
#define OFF_FLAGS (OFF_B4 + 8192)
#define OFF_HBUF  (OFF_FLAGS + 4096)
#define OFF_CBUF  (OFF_HBUF + 131072)
#define OFF_XP    (4u*1024*1024)

// ---------- pack W / bias ----------
__global__ void pack_w(const float* __restrict__ Wi, const float* __restrict__ Wf,
                       const float* __restrict__ Wc, const float* __restrict__ Wo,
                       const float* __restrict__ bi, const float* __restrict__ bf_,
                       const float* __restrict__ bc, const float* __restrict__ bo,
                       u16* __restrict__ w4t, float* __restrict__ b4) {
    int n = blockIdx.x;                 // 0..2047
    int gate = n >> 9, c = n & 511;
    const float* W = (gate == 0) ? Wi : (gate == 1) ? Wf : (gate == 2) ? Wc : Wo;
    const float* B = (gate == 0) ? bi : (gate == 1) ? bf_ : (gate == 2) ? bc : bo;
    int k = threadIdx.x * 2;            // 2 per thread
    u32 v = pk2(W[(size_t)k * 512 + c], W[(size_t)(k + 1) * 512 + c]);
    *(u32*)&w4t[(size_t)n * 512 + k] = v;
    if (threadIdx.x == 0) b4[n] = B[c];
}

// ---------- projection GEMM:  xp[m][n] = bf16( x_row(m) . w4t[n] + b4[n] ) ----------
__global__ __launch_bounds__(256, 2)
void gemm_proj(const float* __restrict__ x, const u16* __restrict__ w4t,
               const float* __restrict__ b4, u16* __restrict__ xp,
               int t0, int Tc) {
    __shared__ __align__(16) u16 lA[128 * 64];
    __shared__ __align__(16) u16 lB[128 * 64];

    int ntb = blockIdx.x & 15;
    int mb  = blockIdx.x >> 4;
    int tps = Tc >> 7;                       // tiles per batch strip
    int bstrip = mb / tps, tb = mb % tps;
    const float* Abase = x + (size_t)(bstrip * SEQ + t0 + tb * 128) * 512;
    size_t xprow0 = (size_t)bstrip * Tc + tb * 128;
    int n0 = ntb * 128;

    int tid = threadIdx.x, lane = tid & 63, w = tid >> 6;
    int wm = w >> 1, wn = w & 1;

    f32x4 acc[4][4];
#pragma unroll
    for (int a = 0; a < 4; a++)
#pragma unroll
        for (int b = 0; b < 4; b++) acc[a][b] = (f32x4){0.f, 0.f, 0.f, 0.f};

    for (int kb = 0; kb < 8; kb++) {
        // stage A (fp32 -> bf16)
        {
            int row = tid >> 1, half = tid & 1;
            const float* src = Abase + (size_t)row * 512 + kb * 64 + half * 32;
            u32 tmp[16];
#pragma unroll
            for (int q = 0; q < 8; q++) {
                float4 f = *(const float4*)(src + q * 4);
                tmp[q * 2]     = pk2(f.x, f.y);
                tmp[q * 2 + 1] = pk2(f.z, f.w);
            }
            u16* dst = &lA[row * 64 + half * 32];
#pragma unroll
            for (int q = 0; q < 4; q++)
                *(uint4*)(dst + q * 8) = *(uint4*)&tmp[q * 4];
        }
        // stage B (already bf16)
        {
            int row = tid >> 1, kc = (tid & 1) * 32;
            const u16* src = w4t + (size_t)(n0 + row) * 512 + kb * 64 + kc;
            uint4 v0 = *(const uint4*)(src);
            uint4 v1 = *(const uint4*)(src + 8);
            uint4 v2 = *(const uint4*)(src + 16);
            uint4 v3 = *(const uint4*)(src + 24);
            u16* dst = &lB[row * 64 + kc];
            *(uint4*)(dst) = v0; *(uint4*)(dst + 8) = v1;
            *(uint4*)(dst + 16) = v2; *(uint4*)(dst + 24) = v3;
        }
        __syncthreads();
#pragma unroll
        for (int kt = 0; kt < 2; kt++) {
            bf16x8 a[4], bb[4];
#pragma unroll
            for (int mt = 0; mt < 4; mt++)
                a[mt] = *(const bf16x8*)&lA[(wm * 64 + mt * 16 + (lane & 15)) * 64 + kt * 32 + (lane >> 4) * 8];
#pragma unroll
            for (int nt = 0; nt < 4; nt++)
                bb[nt] = *(const bf16x8*)&lB[(wn * 64 + nt * 16 + (lane & 15)) * 64 + kt * 32 + (lane >> 4) * 8];
#pragma unroll
            for (int mt = 0; mt < 4; mt++)
#pragma unroll
                for (int nt = 0; nt < 4; nt++)
                    acc[mt][nt] = __builtin_amdgcn_mfma_f32_16x16x32_bf16(a[mt], bb[nt], acc[mt][nt], 0, 0, 0);
        }
        __syncthreads();
    }
    // epilogue: + bias, store bf16
#pragma unroll
    for (int nt = 0; nt < 4; nt++) {
        int n = n0 + wn * 64 + nt * 16 + (lane & 15);
        float bv = b4[n];
#pragma unroll
        for (int mt = 0; mt < 4; mt++)
#pragma unroll
            for (int r = 0; r < 4; r++) {
                size_t m = xprow0 + wm * 64 + mt * 16 + (lane >> 4) * 4 + r;
                xp[m * 2048 + n] = f2bf(acc[mt][nt][r] + bv);
            }
    }
}

// ---------- recurrence: pairwise-exchange design ----------
// 8 WGs x 1024 threads: gid = blockIdx>>1 (batch group of 16), H = blockIdx&1 (h-col half).
// Wave w (0..15) owns h-cols [H*256 + w*16, +16) for ALL 4 gates -> gates fully in-register.
// U slice (1MB bf16) persistent in VGPRs: ub[i][g], i=0..7 local-K, 8..15 remote-K.
// Per step: poll peer flag -> issue 8KB peer-h load -> local MFMA (overlap) -> stage ->
//           barrier -> remote MFMA -> gates (in-reg) -> h store (sc1) -> barrier -> flag.
__global__ __launch_bounds__(1024)
void lstm_rec(const float* __restrict__ U0, const float* __restrict__ U1,
              const float* __restrict__ U2, const float* __restrict__ U3,
              const u16* __restrict__ xp, float* __restrict__ out,
              u32* __restrict__ hbuf, int* __restrict__ flags,
              float* __restrict__ cbuf, int t0, int Tc) {
    const int gid = blockIdx.x >> 1;
    const int H   = blockIdx.x & 1;
    const int Hp  = H ^ 1;
    const int tid = threadIdx.x;
    const int w = tid >> 6, lane = tid & 63;
    const int col16 = lane & 15;          // also MFMA A-row / D-col selector
    const int krow  = lane >> 4;          // 0..3
    const int mycol = H * 256 + w * 16 + col16;   // col within each gate's U (0..511)

    __shared__ __align__(16) u16 h_lds[16 * 512];  // [b][col], XOR-swizzled

    int* myflag   = &flags[(gid * 2 + H)  * 16];
    int* peerflag = &flags[(gid * 2 + Hp) * 16];

    // ---- persistent U fragments ----
    const float* Ug[4] = {U0, U1, U2, U3};
    bf16x8 ub[16][4];
#pragma unroll
    for (int i = 0; i < 16; i++) {
        int kbase = ((i < 8) ? (H * 256 + i * 32) : (Hp * 256 + (i - 8) * 32)) + krow * 8;
#pragma unroll
        for (int g = 0; g < 4; g++) {
            union { u16 sh[8]; bf16x8 v; } uu;
#pragma unroll
            for (int j = 0; j < 8; j++)
                uu.sh[j] = f2bf(Ug[g][(size_t)(kbase + j) * 512 + mycol]);
            ub[i][g] = uu.v;
        }
    }

    // ---- c state in registers ----
    float c[4];
    if (t0 == 0) {
        c[0] = c[1] = c[2] = c[3] = 0.f;
    } else {
#pragma unroll
        for (int r = 0; r < 4; r++)
            c[r] = cbuf[((size_t)gid * 16 + krow * 4 + r) * 512 + mycol];
    }

    // ---- prologue: stage full h_{t0-1} into LDS ----
    {
        while (__hip_atomic_load(peerflag, __ATOMIC_RELAXED, __HIP_MEMORY_SCOPE_AGENT) < t0)
            __builtin_amdgcn_s_sleep(1);
        int b  = tid >> 6;            // wave index = batch row -> coalesced
        int u0 = (tid & 63) * 4;      // u32 index
        const u32* src = hbuf + (size_t)((t0 - 1) & 1) * 16384 + gid * 4096 + b * 256 + u0;
        u64 v0 = __hip_atomic_load((const u64*)src,       __ATOMIC_RELAXED, __HIP_MEMORY_SCOPE_AGENT);
        u64 v1 = __hip_atomic_load((const u64*)(src + 2), __ATOMIC_RELAXED, __HIP_MEMORY_SCOPE_AGENT);
        u32 byte = ((u32)(b * 1024) + (u32)(u0 * 4)) ^ ((u32)(b & 7) << 4);
        uint4 vv; vv.x = (u32)v0; vv.y = (u32)(v0 >> 32); vv.z = (u32)v1; vv.w = (u32)(v1 >> 32);
        *(uint4*)((char*)h_lds + byte) = vv;
    }
    __syncthreads();

    for (int tl = 0; tl < Tc; tl++) {
        const int t = t0 + tl;

        // xp prefetch (issued early; consumed in gate phase)
        u16 xr[4][4];
#pragma unroll
        for (int g = 0; g < 4; g++)
#pragma unroll
            for (int r = 0; r < 4; r++)
                xr[g][r] = xp[(size_t)((gid * 16 + krow * 4 + r) * Tc + tl) * 2048
                              + g * 512 + mycol];

        f32x4 acc[4];
#pragma unroll
        for (int g = 0; g < 4; g++) acc[g] = (f32x4){0.f, 0.f, 0.f, 0.f};

        if (tl > 0) {
            // wait for peer h_{t-1}
            while (__hip_atomic_load(peerflag, __ATOMIC_RELAXED, __HIP_MEMORY_SCOPE_AGENT) < t)
                __builtin_amdgcn_s_sleep(1);
            // issue peer half load (coalesced 512B/wave)
            int b = tid >> 6;
            int u = Hp * 128 + (tid & 63) * 2;
            u64 pv = __hip_atomic_load(
                (const u64*)(hbuf + (size_t)((t - 1) & 1) * 16384 + gid * 4096 + b * 256 + u),
                __ATOMIC_RELAXED, __HIP_MEMORY_SCOPE_AGENT);

            // local-K MFMA while peer load is in flight
#pragma unroll
            for (int i = 0; i < 8; i++) {
                u32 byte = ((u32)(col16 * 1024) + (u32)((H * 8 + i) * 64) + (u32)(krow * 16))
                           ^ ((u32)(col16 & 7) << 4);
                bf16x8 af = *(const bf16x8*)((const char*)h_lds + byte);
#pragma unroll
                for (int g = 0; g < 4; g++)
                    acc[g] = __builtin_amdgcn_mfma_f32_16x16x32_bf16(af, ub[i][g], acc[g], 0, 0, 0);
            }

            // stage peer half into LDS
            {
                u32 byte = ((u32)(b * 1024) + (u32)(u * 4)) ^ ((u32)(b & 7) << 4);
                uint2 vv; vv.x = (u32)pv; vv.y = (u32)(pv >> 32);
                *(uint2*)((char*)h_lds + byte) = vv;
            }
            __syncthreads();

            // remote-K MFMA
#pragma unroll
            for (int i = 8; i < 16; i++) {
                u32 byte = ((u32)(col16 * 1024) + (u32)((Hp * 8 + (i - 8)) * 64) + (u32)(krow * 16))
                           ^ ((u32)(col16 & 7) << 4);
                bf16x8 af = *(const bf16x8*)((const char*)h_lds + byte);
#pragma unroll
                for (int g = 0; g < 4; g++)
                    acc[g] = __builtin_amdgcn_mfma_f32_16x16x32_bf16(af, ub[i][g], acc[g], 0, 0, 0);
            }
        } else {
            // first step of chunk: everything already staged by prologue
#pragma unroll
            for (int i = 0; i < 16; i++) {
                int kt = (i < 8) ? (H * 8 + i) : (Hp * 8 + (i - 8));
                u32 byte = ((u32)(col16 * 1024) + (u32)(kt * 64) + (u32)(krow * 16))
                           ^ ((u32)(col16 & 7) << 4);
                bf16x8 af = *(const bf16x8*)((const char*)h_lds + byte);
#pragma unroll
                for (int g = 0; g < 4; g++)
                    acc[g] = __builtin_amdgcn_mfma_f32_16x16x32_bf16(af, ub[i][g], acc[g], 0, 0, 0);
            }
        }

        // ---- gates: fully in-register ----
        float hv[4];
#pragma unroll
        for (int r = 0; r < 4; r++) {
            float zi = acc[0][r] + bf2f(xr[0][r]);
            float zf = acc[1][r] + bf2f(xr[1][r]);
            float zg = acc[2][r] + bf2f(xr[2][r]);
            float zo = acc[3][r] + bf2f(xr[3][r]);
            float iv = fmaxf(zi, 0.f), fv = fmaxf(zf, 0.f);
            float gv = tanh_(zg), ov = sigm(zo);
            c[r] = fv * c[r] + iv * gv;
            hv[r] = ov * tanh_(c[r]);
        }

        // ---- publish h: pack col-pairs via shfl, even lanes store u32 ----
        {
            size_t hbase = (size_t)(t & 1) * 16384 + gid * 4096;
#pragma unroll
            for (int r = 0; r < 4; r++) {
                u16 hb = f2bf(hv[r]);
                u32 other = (u32)(unsigned)__shfl_xor((int)hb, 1);
                int b = krow * 4 + r;
                if (!(lane & 1)) {
                    u32 packed = (u32)hb | (other << 16);
                    // own half -> LDS (for next step's local MFMA)
                    u32 byte = ((u32)(b * 1024) + (u32)(mycol * 2)) ^ ((u32)(b & 7) << 4);
                    *(u32*)((char*)h_lds + byte) = packed;
                    // own half -> global (for peer + chunk restart)
                    __hip_atomic_store(hbuf + hbase + b * 256 + (mycol >> 1), packed,
                                       __ATOMIC_RELAXED, __HIP_MEMORY_SCOPE_AGENT);
                }
            }
        }
        __syncthreads();   // drains vmcnt: all h stores at coherence point

        if (tid == 0)
            __hip_atomic_store(myflag, t + 1, __ATOMIC_RELAXED, __HIP_MEMORY_SCOPE_AGENT);

        // out stores after flag publish (off critical path)
#pragma unroll
        for (int r = 0; r < 4; r++)
            out[(size_t)((gid * 16 + krow * 4 + r) * SEQ + t) * 512 + mycol + H * 0 + w * 0] = hv[r];
        // note: mycol already includes H*256 + w*16 + col16
    }

    // save c for next chunk
#pragma unroll
    for (int r = 0; r < 4; r++)
        cbuf[((size_t)gid * 16 + krow * 4 + r) * 512 + mycol] = c[r];
}

// ---------- launch ----------
extern "C" void kernel_launch(void* const* d_in, const int* in_sizes, int n_in,
                              void* d_out, int out_size, void* d_ws, size_t ws_size,
                              hipStream_t stream) {
    const float* x  = (const float*)d_in[0];
    const float* Wg[4] = {(const float*)d_in[1], (const float*)d_in[4],
                          (const float*)d_in[7], (const float*)d_in[10]};
    const float* Ug[4] = {(const float*)d_in[2], (const float*)d_in[5],
                          (const float*)d_in[8], (const float*)d_in[11]};
    const float* Bg[4] = {(const float*)d_in[3], (const float*)d_in[6],
                          (const float*)d_in[9], (const float*)d_in[12]};
    float* out = (float*)d_out;

    char* ws = (char*)d_ws;
    u16*   w4t   = (u16*)(ws + OFF_W4T);
    float* b4    = (float*)(ws + OFF_B4);
    int*   flags = (int*)(ws + OFF_FLAGS);
    u32*   hbuf  = (u32*)(ws + OFF_HBUF);
    float* cbuf  = (float*)(ws + OFF_CBUF);
    u16*   xp    = (u16*)(ws + OFF_XP);

    // pick chunk length that fits ws
    int Tc = 128;
    for (int c = 1024; c >= 128; c >>= 1)
        if ((size_t)OFF_XP + (size_t)BS * c * 2048 * 2 <= ws_size) { Tc = c; break; }

    // zero flags + h double-buffer (h_{-1} = 0)
    hipMemsetAsync(ws + OFF_FLAGS, 0, 4096 + 131072, stream);

    pack_w<<<2048, 256, 0, stream>>>(Wg[0], Wg[1], Wg[2], Wg[3],
                                     Bg[0], Bg[1], Bg[2], Bg[3], w4t, b4);

    for (int t0 = 0; t0 < SEQ; t0 += Tc) {
        dim3 ggrid((unsigned)(BS * (Tc / 128) * 16));
        gemm_proj<<<ggrid, 256, 0, stream>>>(x, w4t, b4, xp, t0, Tc);
        lstm_rec<<<8, 1024, 0, stream>>>(Ug[0], Ug[1], Ug[2], Ug[3],
                                         xp, out, hbuf, flags, cbuf, t0, Tc);
    }
}

// Round 3
// 3876.351 us; speedup vs baseline: 7.4682x; 7.4682x over previous
//
#include <hip/hip_runtime.h>
#include <hip/hip_bf16.h>
#include <stdint.h>

typedef float  f32x4  __attribute__((ext_vector_type(4)));
typedef short  bf16x8 __attribute__((ext_vector_type(8)));
typedef unsigned int  u32;
typedef unsigned short u16;
typedef unsigned long long u64;

#define BS    64
#define SEQ   1024
#define HID   512

// ---------- helpers ----------
__device__ __forceinline__ u16 f2bf(float f) {
    u32 u = __float_as_uint(f);
    u32 r = (u + 0x7FFFu + ((u >> 16) & 1u)) >> 16;   // RNE
    return (u16)r;
}
__device__ __forceinline__ float bf2f(u16 h) {
    return __uint_as_float(((u32)h) << 16);
}
__device__ __forceinline__ u32 pk2(float a, float b) {
    return (u32)f2bf(a) | ((u32)f2bf(b) << 16);
}
__device__ __forceinline__ float sigm(float x)  { return 1.f / (1.f + __expf(-x)); }
__device__ __forceinline__ float tanh_(float x) { return 1.f - 2.f / (1.f + __expf(2.f * x)); }

// ---------- ws layout ----------
// [0, 2MB)            w4t  bf16 [2048][512]
// [2MB, +8KB)         b4   f32  [2048]
// [.., +256KB)        hbuf u64  [2][4][16][256]   tagged: u32 = (h_bf16<<16)|tag
// [.., +128KB)        cbuf f32  [4][16][512]
// [4MB, ...)          xp   bf16 [64*Tc][2048]
#define OFF_W4T   0
#define OFF_B4    (2u*1024*1024)
#define OFF_HBUF  (OFF_B4 + 8192)
#define OFF_CBUF  (OFF_HBUF + 262144)
#define OFF_XP    (4u*1024*1024)

// ---------- pack W / bias ----------
__global__ void pack_w(const float* __restrict__ Wi, const float* __restrict__ Wf,
                       const float* __restrict__ Wc, const float* __restrict__ Wo,
                       const float* __restrict__ bi, const float* __restrict__ bf_,
                       const float* __restrict__ bc, const float* __restrict__ bo,
                       u16* __restrict__ w4t, float* __restrict__ b4) {
    int n = blockIdx.x;                 // 0..2047
    int gate = n >> 9, c = n & 511;
    const float* W = (gate == 0) ? Wi : (gate == 1) ? Wf : (gate == 2) ? Wc : Wo;
    const float* B = (gate == 0) ? bi : (gate == 1) ? bf_ : (gate == 2) ? bc : bo;
    int k = threadIdx.x * 2;            // 2 per thread
    u32 v = pk2(W[(size_t)k * 512 + c], W[(size_t)(k + 1) * 512 + c]);
    *(u32*)&w4t[(size_t)n * 512 + k] = v;
    if (threadIdx.x == 0) b4[n] = B[c];
}

// ---------- projection GEMM:  xp[m][n] = bf16( x_row(m) . w4t[n] + b4[n] ) ----------
__global__ __launch_bounds__(256, 2)
void gemm_proj(const float* __restrict__ x, const u16* __restrict__ w4t,
               const float* __restrict__ b4, u16* __restrict__ xp,
               int t0, int Tc) {
    __shared__ __align__(16) u16 lA[128 * 64];
    __shared__ __align__(16) u16 lB[128 * 64];

    int ntb = blockIdx.x & 15;
    int mb  = blockIdx.x >> 4;
    int tps = Tc >> 7;                       // tiles per batch strip
    int bstrip = mb / tps, tb = mb % tps;
    const float* Abase = x + (size_t)(bstrip * SEQ + t0 + tb * 128) * 512;
    size_t xprow0 = (size_t)bstrip * Tc + tb * 128;
    int n0 = ntb * 128;

    int tid = threadIdx.x, lane = tid & 63, w = tid >> 6;
    int wm = w >> 1, wn = w & 1;

    f32x4 acc[4][4];
#pragma unroll
    for (int a = 0; a < 4; a++)
#pragma unroll
        for (int b = 0; b < 4; b++) acc[a][b] = (f32x4){0.f, 0.f, 0.f, 0.f};

    for (int kb = 0; kb < 8; kb++) {
        // stage A (fp32 -> bf16)
        {
            int row = tid >> 1, half = tid & 1;
            const float* src = Abase + (size_t)row * 512 + kb * 64 + half * 32;
            u32 tmp[16];
#pragma unroll
            for (int q = 0; q < 8; q++) {
                float4 f = *(const float4*)(src + q * 4);
                tmp[q * 2]     = pk2(f.x, f.y);
                tmp[q * 2 + 1] = pk2(f.z, f.w);
            }
            u16* dst = &lA[row * 64 + half * 32];
#pragma unroll
            for (int q = 0; q < 4; q++)
                *(uint4*)(dst + q * 8) = *(uint4*)&tmp[q * 4];
        }
        // stage B (already bf16)
        {
            int row = tid >> 1, kc = (tid & 1) * 32;
            const u16* src = w4t + (size_t)(n0 + row) * 512 + kb * 64 + kc;
            uint4 v0 = *(const uint4*)(src);
            uint4 v1 = *(const uint4*)(src + 8);
            uint4 v2 = *(const uint4*)(src + 16);
            uint4 v3 = *(const uint4*)(src + 24);
            u16* dst = &lB[row * 64 + kc];
            *(uint4*)(dst) = v0; *(uint4*)(dst + 8) = v1;
            *(uint4*)(dst + 16) = v2; *(uint4*)(dst + 24) = v3;
        }
        __syncthreads();
#pragma unroll
        for (int kt = 0; kt < 2; kt++) {
            bf16x8 a[4], bb[4];
#pragma unroll
            for (int mt = 0; mt < 4; mt++)
                a[mt] = *(const bf16x8*)&lA[(wm * 64 + mt * 16 + (lane & 15)) * 64 + kt * 32 + (lane >> 4) * 8];
#pragma unroll
            for (int nt = 0; nt < 4; nt++)
                bb[nt] = *(const bf16x8*)&lB[(wn * 64 + nt * 16 + (lane & 15)) * 64 + kt * 32 + (lane >> 4) * 8];
#pragma unroll
            for (int mt = 0; mt < 4; mt++)
#pragma unroll
                for (int nt = 0; nt < 4; nt++)
                    acc[mt][nt] = __builtin_amdgcn_mfma_f32_16x16x32_bf16(a[mt], bb[nt], acc[mt][nt], 0, 0, 0);
        }
        __syncthreads();
    }
    // epilogue: + bias, store bf16
#pragma unroll
    for (int nt = 0; nt < 4; nt++) {
        int n = n0 + wn * 64 + nt * 16 + (lane & 15);
        float bv = b4[n];
#pragma unroll
        for (int mt = 0; mt < 4; mt++)
#pragma unroll
            for (int r = 0; r < 4; r++) {
                size_t m = xprow0 + wm * 64 + mt * 16 + (lane >> 4) * 4 + r;
                xp[m * 2048 + n] = f2bf(acc[mt][nt][r] + bv);
            }
    }
}

// ---------- recurrence: tagged-data exchange ----------
// 32 WGs x 256 threads: gid = blockIdx>>3 (batch group of 16 rows), q = blockIdx&7
// (64 h-cols). Wave w owns h-cols [q*64+w*16, +16) for ALL 4 gates -> gates in-register.
// U slice persistent in VGPRs: ub[16][4] = 256 VGPRs (needs 1 wave/SIMD -> 512 cap).
// Exchange: h stored as tagged u32 (h_bf16<<16 | (t+1)); consumers spin on the DATA
// until all tags == t. No flags, no producer drain, ~1 MALL round-trip per step.
__global__ __launch_bounds__(256, 1)
void lstm_rec(const float* __restrict__ U0, const float* __restrict__ U1,
              const float* __restrict__ U2, const float* __restrict__ U3,
              const u16* __restrict__ xp, float* __restrict__ out,
              u64* __restrict__ hb, float* __restrict__ cbuf, int t0, int Tc) {
    const int gid = blockIdx.x >> 3;
    const int q   = blockIdx.x & 7;
    const int tid = threadIdx.x;
    const int w = tid >> 6, lane = tid & 63;
    const int col16 = lane & 15;
    const int krow  = lane >> 4;                  // 0..3
    const int mycol = q * 64 + w * 16 + col16;    // h-col 0..511

    __shared__ __align__(16) u16 h_lds[2][16 * 512];   // double-buffered, XOR-swizzled

    // ---- persistent U fragments: ub[kt][gate] ----
    const float* Ug[4] = {U0, U1, U2, U3};
    bf16x8 ub[16][4];
#pragma unroll
    for (int kt = 0; kt < 16; kt++) {
        int kbase = kt * 32 + krow * 8;
#pragma unroll
        for (int g = 0; g < 4; g++) {
            union { u16 sh[8]; bf16x8 v; } uu;
#pragma unroll
            for (int j = 0; j < 8; j++)
                uu.sh[j] = f2bf(Ug[g][(size_t)(kbase + j) * 512 + mycol]);
            ub[kt][g] = uu.v;
        }
    }

    // ---- c state in registers (rows krow*4+r) ----
    float c[4];
    if (t0 == 0) {
        c[0] = c[1] = c[2] = c[3] = 0.f;
    } else {
#pragma unroll
        for (int r = 0; r < 4; r++)
            c[r] = cbuf[((size_t)gid * 16 + krow * 4 + r) * 512 + mycol];
    }

    for (int tl = 0; tl < Tc; tl++) {
        const int t = t0 + tl;

        // xp prefetch (independent of exchange)
        u16 xr[4][4];
#pragma unroll
        for (int g = 0; g < 4; g++)
#pragma unroll
            for (int r = 0; r < 4; r++)
                xr[g][r] = xp[(size_t)((gid * 16 + krow * 4 + r) * Tc + tl) * 2048
                              + g * 512 + mycol];

        // ---- tagged spin-load of h_{t-1}: thread owns col-pair `tid` of all 16 rows ----
        u32 hp[16];
        {
            const u64* src = hb + (((size_t)((t + 1) & 1)) << 14) + ((size_t)gid << 12) + tid;
            const u32 te = (u32)t & 0xFFFFu;
            for (;;) {
                u64 v[16];
#pragma unroll
                for (int j = 0; j < 16; j++)
                    v[j] = __hip_atomic_load(src + j * 256, __ATOMIC_RELAXED,
                                             __HIP_MEMORY_SCOPE_AGENT);
                u32 ok = 1;
#pragma unroll
                for (int j = 0; j < 16; j++) {
                    u32 w0 = (u32)v[j], w1 = (u32)(v[j] >> 32);
                    ok &= (u32)((w0 & 0xFFFFu) == te) & (u32)((w1 & 0xFFFFu) == te);
                }
                if (ok) {
#pragma unroll
                    for (int j = 0; j < 16; j++)
                        hp[j] = ((u32)v[j] >> 16) | ((u32)(v[j] >> 32) & 0xFFFF0000u);
                    break;
                }
            }
        }

        // ---- stage to LDS (buffer t&1), swizzled ----
        u16* hl = &h_lds[t & 1][0];
#pragma unroll
        for (int j = 0; j < 16; j++) {
            u32 byte = ((u32)(j * 1024) + (u32)(tid * 4)) ^ ((u32)(j & 7) << 4);
            *(u32*)((char*)hl + byte) = hp[j];
        }
        __syncthreads();

        // ---- z = h @ U : 64 MFMAs/wave, gates in-register ----
        f32x4 acc[4];
#pragma unroll
        for (int g = 0; g < 4; g++) acc[g] = (f32x4){0.f, 0.f, 0.f, 0.f};
#pragma unroll
        for (int kt = 0; kt < 16; kt++) {
            u32 byte = ((u32)(col16 * 1024) + (u32)(kt * 64) + (u32)(krow * 16))
                       ^ ((u32)(col16 & 7) << 4);
            bf16x8 af = *(const bf16x8*)((const char*)hl + byte);
#pragma unroll
            for (int g = 0; g < 4; g++)
                acc[g] = __builtin_amdgcn_mfma_f32_16x16x32_bf16(af, ub[kt][g], acc[g], 0, 0, 0);
        }

        // ---- gates ----
        float hv[4];
#pragma unroll
        for (int r = 0; r < 4; r++) {
            float zi = acc[0][r] + bf2f(xr[0][r]);
            float zf = acc[1][r] + bf2f(xr[1][r]);
            float zg = acc[2][r] + bf2f(xr[2][r]);
            float zo = acc[3][r] + bf2f(xr[3][r]);
            float iv = fmaxf(zi, 0.f), fv = fmaxf(zf, 0.f);
            float gv = tanh_(zg), ov = sigm(zo);
            c[r] = fv * c[r] + iv * gv;
            hv[r] = ov * tanh_(c[r]);
        }

        // ---- publish tagged h_t (no drain, no flag) ----
        {
            const u32 tag = (u32)((t + 1) & 0xFFFF);
            u32* dst = (u32*)(hb + (((size_t)(t & 1)) << 14) + ((size_t)gid << 12));
#pragma unroll
            for (int r = 0; r < 4; r++) {
                int row = krow * 4 + r;
                u32 word = ((u32)f2bf(hv[r]) << 16) | tag;
                __hip_atomic_store(dst + row * 512 + mycol, word, __ATOMIC_RELAXED,
                                   __HIP_MEMORY_SCOPE_AGENT);
            }
        }

        // ---- output stores (off critical path) ----
#pragma unroll
        for (int r = 0; r < 4; r++)
            out[(size_t)((gid * 16 + krow * 4 + r) * SEQ + t) * 512 + mycol] = hv[r];
    }

    // save c for next chunk
#pragma unroll
    for (int r = 0; r < 4; r++)
        cbuf[((size_t)gid * 16 + krow * 4 + r) * 512 + mycol] = c[r];
}

// ---------- launch ----------
extern "C" void kernel_launch(void* const* d_in, const int* in_sizes, int n_in,
                              void* d_out, int out_size, void* d_ws, size_t ws_size,
                              hipStream_t stream) {
    const float* x  = (const float*)d_in[0];
    const float* Wg[4] = {(const float*)d_in[1], (const float*)d_in[4],
                          (const float*)d_in[7], (const float*)d_in[10]};
    const float* Ug[4] = {(const float*)d_in[2], (const float*)d_in[5],
                          (const float*)d_in[8], (const float*)d_in[11]};
    const float* Bg[4] = {(const float*)d_in[3], (const float*)d_in[6],
                          (const float*)d_in[9], (const float*)d_in[12]};
    float* out = (float*)d_out;

    char* ws = (char*)d_ws;
    u16*   w4t   = (u16*)(ws + OFF_W4T);
    float* b4    = (float*)(ws + OFF_B4);
    u64*   hb    = (u64*)(ws + OFF_HBUF);
    float* cbuf  = (float*)(ws + OFF_CBUF);
    u16*   xp    = (u16*)(ws + OFF_XP);

    // pick chunk length that fits ws
    int Tc = 128;
    for (int c = 1024; c >= 128; c >>= 1)
        if ((size_t)OFF_XP + (size_t)BS * c * 2048 * 2 <= ws_size) { Tc = c; break; }

    // zero tagged hbuf: tag 0 == "h_{-1} ready, value 0"
    hipMemsetAsync(ws + OFF_HBUF, 0, 262144, stream);

    pack_w<<<2048, 256, 0, stream>>>(Wg[0], Wg[1], Wg[2], Wg[3],
                                     Bg[0], Bg[1], Bg[2], Bg[3], w4t, b4);

    for (int t0 = 0; t0 < SEQ; t0 += Tc) {
        dim3 ggrid((unsigned)(BS * (Tc / 128) * 16));
        gemm_proj<<<ggrid, 256, 0, stream>>>(x, w4t, b4, xp, t0, Tc);
        lstm_rec<<<32, 256, 0, stream>>>(Ug[0], Ug[1], Ug[2], Ug[3],
                                         xp, out, hb, cbuf, t0, Tc);
    }
}